// Round 10
// baseline (90.079 us; speedup 1.0000x reference)
//
#include <hip/hip_runtime.h>
#include <float.h>

// Problem constants (match reference)
#define BB 32
#define CC 256
#define SS 64
#define IMG (SS * SS)          // 4096 pixels per (b,c) image
#define NTOT (BB * CC * IMG)   // 33554432 total elements

typedef float  f32x4 __attribute__((ext_vector_type(4)));
typedef ushort u16x4 __attribute__((ext_vector_type(4)));
typedef ushort u16x8 __attribute__((ext_vector_type(8)));
typedef uint   u32x4 __attribute__((ext_vector_type(4)));

// ws layout (float offsets) — partials ~272 KB, then bf16 shadow copy of x
#define WPM_OFF 0              // wpart_max[32][16][64]
#define WPS_OFF 32768          // wpart_sum[32][16][64]
#define HMX_OFF 65536          // hmax[32][64]
#define HSM_OFF 67584          // hsum[32][64]
#define XB_BYTE_OFF (69632 * 4)        // ushort xbf16[NTOT] starts here (8-B aligned)

__device__ __forceinline__ f32x4 f4max(f32x4 a, f32x4 b) {
    f32x4 r;
    r.x = fmaxf(a.x, b.x); r.y = fmaxf(a.y, b.y);
    r.z = fmaxf(a.z, b.z); r.w = fmaxf(a.w, b.w);
    return r;
}
__device__ __forceinline__ f32x4 shfl_xor4(f32x4 v, int m) {
    f32x4 r;
    r.x = __shfl_xor(v.x, m); r.y = __shfl_xor(v.y, m);
    r.z = __shfl_xor(v.z, m); r.w = __shfl_xor(v.w, m);
    return r;
}
__device__ __forceinline__ float allreduce_sum(float v) {
#pragma unroll
    for (int o = 32; o > 0; o >>= 1) v += __shfl_xor(v, o);
    return v;
}
__device__ __forceinline__ float allreduce_max(float v) {
#pragma unroll
    for (int o = 32; o > 0; o >>= 1) v = fmaxf(v, __shfl_xor(v, o));
    return v;
}
__device__ __forceinline__ ushort f2bf_rne(float f) {      // round-to-nearest-even
    uint u = __builtin_bit_cast(uint, f);
    u += 0x7FFFu + ((u >> 16) & 1u);
    return (ushort)(u >> 16);
}

__device__ __forceinline__ float branch_lane(float meanv, float maxv,
                                             float w0, float w1, float w2,
                                             float b0, float b1, float b2) {
    float m  = allreduce_max(meanv);
    float e  = expf(meanv - m);
    float s  = e / allreduce_sum(e);
    float y0 = allreduce_sum(meanv * w0);
    float y1 = allreduce_sum(maxv * w1);
    float y0t = tanhf(fmaf(y0, s, b0));
    float y1t = tanhf(fmaf(y1, s, b1));
    float yw2 = allreduce_sum(y1t * w2);
    return fmaf(yw2, y0t, b2);
}

// ---------------- Kernel 1: channel reduction -> tiny partials (+ bf16 copy) ----------------
// R9-proven logic; template adds the bf16 shadow-copy store.
template <bool WRITE_BF16>
__global__ __launch_bounds__(256) void reduce_part_kernel(const float* __restrict__ x,
                                                          float* __restrict__ ws,
                                                          ushort* __restrict__ xb) {
    const int blk  = blockIdx.x;
    const int b    = blk >> 4;
    const int j    = blk & 15;
    const int tid  = threadIdx.x;
    const int wave = tid >> 6;
    const int lane = tid & 63;
    const int pos0 = j << 8;

    const size_t base = ((size_t)(b * CC + wave * 64) << 12) + pos0 + (lane << 2);
    const float* xp = x + base;
    f32x4 vmax = (f32x4)(-FLT_MAX);
    f32x4 vsum = (f32x4)(0.f);
#pragma unroll 16
    for (int c = 0; c < 64; ++c) {
        f32x4 v = *(const f32x4*)(xp + ((size_t)c << 12));
        vmax = f4max(vmax, v);
        vsum += v;
        if (WRITE_BF16) {
            u16x4 bv;
            bv.x = f2bf_rne(v.x); bv.y = f2bf_rne(v.y);
            bv.z = f2bf_rne(v.z); bv.w = f2bf_rne(v.w);
            *(u16x4*)(xb + base + ((size_t)c << 12)) = bv;   // 8 B/thread, wave-contiguous
        }
    }

    __shared__ f32x4 smax[4][64];
    __shared__ f32x4 ssum[4][64];
    smax[wave][lane] = vmax;
    ssum[wave][lane] = vsum;
    __syncthreads();

    if (wave == 0) {
        f32x4 m  = smax[0][lane];
        f32x4 sm = ssum[0][lane];
#pragma unroll
        for (int w = 1; w < 4; ++w) {
            m  = f4max(m, smax[w][lane]);
            sm += ssum[w][lane];
        }
        f32x4 mean = sm * (1.0f / (float)CC);

        float em = fmaxf(fmaxf(m.x, m.y), fmaxf(m.z, m.w));
        float es = mean.x + mean.y + mean.z + mean.w;
#pragma unroll
        for (int o = 1; o < 16; o <<= 1) {
            em = fmaxf(em, __shfl_xor(em, o));
            es += __shfl_xor(es, o);
        }
        if ((lane & 15) == 0) {
            const int row = 4 * j + (lane >> 4);
            ws[HMX_OFF + b * 64 + row] = em;
            ws[HSM_OFF + b * 64 + row] = es;
        }
        f32x4 cm = m, cs = mean;
        cm = f4max(cm, shfl_xor4(cm, 16));
        cm = f4max(cm, shfl_xor4(cm, 32));
        cs += shfl_xor4(cs, 16);
        cs += shfl_xor4(cs, 32);
        if (lane < 16) {
            *(f32x4*)(ws + WPM_OFF + (b * 16 + j) * 64 + lane * 4) = cm;
            *(f32x4*)(ws + WPS_OFF + (b * 16 + j) * 64 + lane * 4) = cs;
        }
    }
}

// ---------------- Kernel 2: branch (from partials) + apply ----------------
// FROM_BF16: read the 67 MB shadow copy (likely L3-resident) instead of fp32 x.
template <bool FROM_BF16>
__global__ __launch_bounds__(256) void branch_apply_kernel(
        const float* __restrict__ x, const ushort* __restrict__ xb,
        const float* __restrict__ ws,
        const float* __restrict__ ww0, const float* __restrict__ ww1, const float* __restrict__ ww2,
        const float* __restrict__ wb0, const float* __restrict__ wb1, const float* __restrict__ wb2,
        const float* __restrict__ hw0, const float* __restrict__ hw1, const float* __restrict__ hw2,
        const float* __restrict__ hb0, const float* __restrict__ hb1, const float* __restrict__ hb2,
        float* __restrict__ out) {
    const int blk  = blockIdx.x;
    const int b    = blk >> 5;
    const int g    = blk & 31;
    const int tid  = threadIdx.x;
    const int wave = tid >> 6;
    const int lane = tid & 63;

    __shared__ float sh_w[64], sh_h[64];
    if (wave == 0) {
        float wm = -FLT_MAX, wsv = 0.f;
#pragma unroll 4
        for (int j = 0; j < 16; ++j) {
            wm  = fmaxf(wm, ws[WPM_OFF + (b * 16 + j) * 64 + lane]);
            wsv += ws[WPS_OFF + (b * 16 + j) * 64 + lane];
        }
        sh_w[lane] = branch_lane(wsv * (1.0f / (float)SS), wm,
                                 ww0[lane], ww1[lane], ww2[lane],
                                 wb0[lane], wb1[lane], wb2[lane]);
    } else if (wave == 1) {
        float hm = ws[HMX_OFF + b * 64 + lane];
        float hs = ws[HSM_OFF + b * 64 + lane];
        sh_h[lane] = branch_lane(hs * (1.0f / (float)SS), hm,
                                 hw0[lane], hw1[lane], hw2[lane],
                                 hb0[lane], hb1[lane], hb2[lane]);
    }
    __syncthreads();

    __shared__ float sp[IMG];          // (tanh+1) tile, built once, reused by 8 channels
#pragma unroll 4
    for (int p = tid; p < IMG; p += 256) {
        sp[p] = tanhf(sh_h[p >> 6] * sh_w[p & 63]) + 1.0f;
    }
    __syncthreads();

    const size_t cbase = (size_t)(b * CC + g * 8) << 12;
    float* op = out + cbase;
    if (FROM_BF16) {
        const ushort* xbp = xb + cbase;
#pragma unroll
        for (int c = 0; c < 8; ++c) {
            const u16x8* xc = (const u16x8*)(xbp + ((size_t)c << 12));
            f32x4*       oc = (f32x4*)(op + ((size_t)c << 12));
#pragma unroll
            for (int p8 = tid; p8 < IMG / 8; p8 += 256) {     // 2 iters: 8 px/thread, 16-B loads
                u16x8 hv = xc[p8];
                f32x4 a, bq;
                a.x  = __builtin_bit_cast(float, (uint)hv.s0 << 16);
                a.y  = __builtin_bit_cast(float, (uint)hv.s1 << 16);
                a.z  = __builtin_bit_cast(float, (uint)hv.s2 << 16);
                a.w  = __builtin_bit_cast(float, (uint)hv.s3 << 16);
                bq.x = __builtin_bit_cast(float, (uint)hv.s4 << 16);
                bq.y = __builtin_bit_cast(float, (uint)hv.s5 << 16);
                bq.z = __builtin_bit_cast(float, (uint)hv.s6 << 16);
                bq.w = __builtin_bit_cast(float, (uint)hv.s7 << 16);
                f32x4 sa = *(const f32x4*)(sp + p8 * 8);
                f32x4 sb = *(const f32x4*)(sp + p8 * 8 + 4);
                __builtin_nontemporal_store(a * sa,  oc + p8 * 2);
                __builtin_nontemporal_store(bq * sb, oc + p8 * 2 + 1);
            }
        }
    } else {
        const float* xp = x + cbase;
#pragma unroll
        for (int c = 0; c < 8; ++c) {
            const f32x4* xc = (const f32x4*)(xp + ((size_t)c << 12));
            f32x4*       oc = (f32x4*)(op + ((size_t)c << 12));
#pragma unroll
            for (int p4 = tid; p4 < IMG / 4; p4 += 256) {
                f32x4 v = xc[p4];
                f32x4 s = *(const f32x4*)(sp + p4 * 4);
                __builtin_nontemporal_store(v * s, oc + p4);
            }
        }
    }
}

extern "C" void kernel_launch(void* const* d_in, const int* in_sizes, int n_in,
                              void* d_out, int out_size, void* d_ws, size_t ws_size,
                              hipStream_t stream) {
    const float* x   = (const float*)d_in[0];
    const float* ww0 = (const float*)d_in[1];
    const float* ww1 = (const float*)d_in[2];
    const float* ww2 = (const float*)d_in[3];
    const float* wb0 = (const float*)d_in[4];
    const float* wb1 = (const float*)d_in[5];
    const float* wb2 = (const float*)d_in[6];
    const float* hw0 = (const float*)d_in[7];
    const float* hw1 = (const float*)d_in[8];
    const float* hw2 = (const float*)d_in[9];
    const float* hb0 = (const float*)d_in[10];
    const float* hb1 = (const float*)d_in[11];
    const float* hb2 = (const float*)d_in[12];
    float* out = (float*)d_out;
    float* ws  = (float*)d_ws;
    ushort* xb = (ushort*)((char*)d_ws + XB_BYTE_OFF);

    const bool use_bf16 = ws_size >= (size_t)XB_BYTE_OFF + (size_t)NTOT * sizeof(ushort);

    if (use_bf16) {
        reduce_part_kernel<true><<<512, 256, 0, stream>>>(x, ws, xb);
        branch_apply_kernel<true><<<1024, 256, 0, stream>>>(x, xb, ws,
                ww0, ww1, ww2, wb0, wb1, wb2,
                hw0, hw1, hw2, hb0, hb1, hb2, out);
    } else {
        reduce_part_kernel<false><<<512, 256, 0, stream>>>(x, ws, xb);
        branch_apply_kernel<false><<<1024, 256, 0, stream>>>(x, xb, ws,
                ww0, ww1, ww2, wb0, wb1, wb2,
                hw0, hw1, hw2, hb0, hb1, hb2, out);
    }
}